// Round 4
// baseline (169.618 us; speedup 1.0000x reference)
//
#include <hip/hip_runtime.h>
#include <hip/hip_bf16.h>

#define NV 100000
#define ND 64
#define NB 4096
#define NL 200
#define HST 72   // histA row stride in bf16 elems (144 B) -> b128 frag reads conflict-light

typedef __bf16 bf16_t;
typedef __bf16 bf16x8 __attribute__((ext_vector_type(8)));
typedef float  f32x4  __attribute__((ext_vector_type(4)));

// f32 table -> bf16 table in ws. 800000 threads x 8 elems = 6.4M exactly.
__global__ __launch_bounds__(256)
void din_cvt(const float* __restrict__ emb, bf16_t* __restrict__ embh)
{
    const long base = ((long)blockIdx.x * 256 + threadIdx.x) * 8;
    f32x4 a0 = *(const f32x4*)(emb + base);
    f32x4 a1 = *(const f32x4*)(emb + base + 4);
    bf16x8 o;
    #pragma unroll
    for (int i = 0; i < 4; ++i) { o[i] = (bf16_t)a0[i]; o[i + 4] = (bf16_t)a1[i]; }
    *(bf16x8*)(embh + base) = o;
}

template <bool BT>
__global__ __launch_bounds__(256, 5)
void din_kernel1(const int* __restrict__ item_ids,
                 const int* __restrict__ history,
                 const int* __restrict__ hist_len,
                 const float* __restrict__ emb,
                 const bf16_t* __restrict__ embh,
                 const float* __restrict__ aW1,
                 const float* __restrict__ ab1,
                 const float* __restrict__ aW2,
                 float* __restrict__ comb_ws)
{
    __shared__ __align__(16) bf16_t histA[208 * HST];
    __shared__ __align__(16) float sc_w[208];
    __shared__ float pp[256];
    __shared__ float tgt[64];
    __shared__ float cb[64];
    __shared__ float pooled[64];
    __shared__ float red[8];

    const int b    = blockIdx.x;
    const int tid  = threadIdx.x;
    const int item = item_ids[b];
    const int len  = hist_len[b];                  // [1, 200]
    const int wave = tid >> 6, lane = tid & 63;
    const int col  = lane & 15, quad = lane >> 4;

    if (tid < 64) tgt[tid] = emb[(long)item * ND + tid];

    // ---- phase 1: gather history rows -> LDS ----
    if constexpr (BT) {
        // bf16 table: 128-B rows, 2 lanes per row, 2 passes of 128 rows
        const int p  = tid & 1;     // half-row: 32 bf16 = 64 B
        const int lb = tid >> 1;    // 0..127
        const int l1 = 128 + lb;    // 128..255
        const int i0 = history[b * NL + (lb < NL ? lb : NL - 1)];
        const int i1 = history[b * NL + (l1 < NL ? l1 : NL - 1)];
        const bool v0 = lb < len, v1 = l1 < len;
        const bf16x8 z = (bf16x8)(bf16_t)0.f;
        bf16x8 r0[4] = {z, z, z, z}, r1[4] = {z, z, z, z};
        if (v0) {
            const bf16_t* s = embh + (long)i0 * ND + p * 32;
            #pragma unroll
            for (int j = 0; j < 4; ++j) r0[j] = *(const bf16x8*)(s + j * 8);
        }
        if (v1) {
            const bf16_t* s = embh + (long)i1 * ND + p * 32;
            #pragma unroll
            for (int j = 0; j < 4; ++j) r1[j] = *(const bf16x8*)(s + j * 8);
        }
        bf16_t* d0 = &histA[lb * HST + p * 32];
        #pragma unroll
        for (int j = 0; j < 4; ++j) *(bf16x8*)(d0 + j * 8) = r0[j];
        if (l1 < 208) {
            bf16_t* d1 = &histA[l1 * HST + p * 32];
            #pragma unroll
            for (int j = 0; j < 4; ++j) *(bf16x8*)(d1 + j * 8) = r1[j];
        }
    } else {
        // f32 table fallback: 256-B rows, 4 lanes per row, 4 passes of 64 rows
        const int p     = tid & 3;
        const int lbase = tid >> 2;
        int  idxs[4]; bool vs[4];
        #pragma unroll
        for (int pass = 0; pass < 4; ++pass) {
            int l  = pass * 64 + lbase;
            idxs[pass] = history[b * NL + (l < NL ? l : NL - 1)];
            vs[pass]   = l < len;
        }
        #pragma unroll
        for (int g = 0; g < 2; ++g) {
            f32x4 r[2][4];
            #pragma unroll
            for (int q = 0; q < 2; ++q) {
                int pass = g * 2 + q, l = pass * 64 + lbase;
                if (l < 208 && vs[pass]) {
                    const float* src = emb + (long)idxs[pass] * ND + p * 16;
                    #pragma unroll
                    for (int j = 0; j < 4; ++j) r[q][j] = *(const f32x4*)(src + j * 4);
                }
            }
            #pragma unroll
            for (int q = 0; q < 2; ++q) {
                int pass = g * 2 + q, l = pass * 64 + lbase;
                if (l < 208) {
                    bf16x8 o0 = (bf16x8)(bf16_t)0.f, o1 = (bf16x8)(bf16_t)0.f;
                    if (vs[pass]) {
                        #pragma unroll
                        for (int i = 0; i < 4; ++i) {
                            o0[i] = (bf16_t)r[q][0][i]; o0[i + 4] = (bf16_t)r[q][1][i];
                            o1[i] = (bf16_t)r[q][2][i]; o1[i + 4] = (bf16_t)r[q][3][i];
                        }
                    }
                    bf16_t* dst = &histA[l * HST + p * 16];
                    *(bf16x8*)(dst) = o0;
                    *(bf16x8*)(dst + 8) = o1;
                }
            }
        }
    }

    // ---- phase 2a: cb partials (tgt-term through middle 64 rows of aW1) ----
    {
        const int n4 = (tid & 15) * 4;
        const int kp = tid >> 4;
        f32x4 t4  = *(const f32x4*)(emb + (long)item * ND + kp * 4);
        f32x4 wb0 = *(const f32x4*)(aW1 + (64 + kp * 4 + 0) * 64 + n4);
        f32x4 wb1 = *(const f32x4*)(aW1 + (64 + kp * 4 + 1) * 64 + n4);
        f32x4 wb2 = *(const f32x4*)(aW1 + (64 + kp * 4 + 2) * 64 + n4);
        f32x4 wb3 = *(const f32x4*)(aW1 + (64 + kp * 4 + 3) * 64 + n4);
        f32x4 c4;
        #pragma unroll
        for (int j = 0; j < 4; ++j)
            c4[j] = t4[0] * wb0[j] + t4[1] * wb1[j] + t4[2] * wb2[j] + t4[3] * wb3[j];
        #pragma unroll
        for (int j = 0; j < 4; ++j) {
            c4[j] += __shfl_xor(c4[j], 16, 64);
            c4[j] += __shfl_xor(c4[j], 32, 64);
        }
        if (lane < 16) *(f32x4*)&pp[wave * 64 + n4] = c4;
    }

    __syncthreads();   // histA + pp + tgt visible

    if (tid < 64) cb[tid] = ab1[tid] + pp[tid] + pp[64 + tid] + pp[128 + tid] + pp[192 + tid];

    // ---- B-frags per lane from global aW1 (L2-hot 48 KB) ----
    bf16x8 bfrag[4][2];
    #pragma unroll
    for (int kb = 0; kb < 2; ++kb) {
        f32x4 t0 = *(const f32x4*)&tgt[kb * 32 + quad * 8];
        f32x4 t1 = *(const f32x4*)&tgt[kb * 32 + quad * 8 + 4];
        #pragma unroll
        for (int nt = 0; nt < 4; ++nt) {
            const int n = nt * 16 + col;
            const float* pa = aW1 + (long)(kb * 32 + quad * 8) * 64 + n;
            const float* pc = pa + 128 * 64;
            float wa[8], wc[8];
            #pragma unroll
            for (int j = 0; j < 8; ++j) { wa[j] = pa[j * 64]; wc[j] = pc[j * 64]; }
            bf16x8 w;
            #pragma unroll
            for (int j = 0; j < 8; ++j) {
                float tk = (j < 4) ? t0[j] : t1[j - 4];
                w[j] = (bf16_t)(wa[j] + tk * wc[j]);
            }
            bfrag[nt][kb] = w;
        }
    }
    float a2vals[4];
    #pragma unroll
    for (int nt = 0; nt < 4; ++nt) a2vals[nt] = aW2[nt * 16 + col];

    __syncthreads();   // cb visible
    float cvals[4];
    #pragma unroll
    for (int nt = 0; nt < 4; ++nt) cvals[nt] = cb[nt * 16 + col];

    // ---- phase 3: scores via MFMA, A-frags from LDS ----
    for (int mt = wave; mt < 13; mt += 4) {
        const bf16_t* arow = &histA[(mt * 16 + col) * HST + quad * 8];
        bf16x8 af0 = *(const bf16x8*)(arow);
        bf16x8 af1 = *(const bf16x8*)(arow + 32);
        float sc[4] = {0.f, 0.f, 0.f, 0.f};
        #pragma unroll
        for (int nt = 0; nt < 4; ++nt) {
            f32x4 acc = {0.f, 0.f, 0.f, 0.f};
            acc = __builtin_amdgcn_mfma_f32_16x16x32_bf16(af0, bfrag[nt][0], acc, 0, 0, 0);
            acc = __builtin_amdgcn_mfma_f32_16x16x32_bf16(af1, bfrag[nt][1], acc, 0, 0, 0);
            #pragma unroll
            for (int i = 0; i < 4; ++i) {
                float h = acc[i] + cvals[nt];
                h = h > 0.f ? h : 0.f;
                sc[i] += h * a2vals[nt];
            }
        }
        #pragma unroll
        for (int off = 1; off < 16; off <<= 1)
            #pragma unroll
            for (int i = 0; i < 4; ++i) sc[i] += __shfl_xor(sc[i], off, 64);
        if (col == 0) {
            f32x4 outv = {sc[0], sc[1], sc[2], sc[3]};
            *(f32x4*)&sc_w[mt * 16 + quad * 4] = outv;
        }
    }
    __syncthreads();

    // ---- phase 4: softmax over exactly L=200 ----
    {
        float s = (tid < NL) ? sc_w[tid] : -1e30f;
        float m = s;
        #pragma unroll
        for (int off = 32; off > 0; off >>= 1) m = fmaxf(m, __shfl_xor(m, off, 64));
        if (lane == 0) red[wave] = m;
        __syncthreads();
        m = fmaxf(fmaxf(red[0], red[1]), fmaxf(red[2], red[3]));
        float e = (tid < NL) ? __expf(s - m) : 0.f;
        float ssum = e;
        #pragma unroll
        for (int off = 32; off > 0; off >>= 1) ssum += __shfl_xor(ssum, off, 64);
        if (lane == 0) red[4 + wave] = ssum;
        __syncthreads();
        float tot = red[4] + red[5] + red[6] + red[7];
        if (tid < NL) sc_w[tid] = e / tot;
    }
    __syncthreads();

    // ---- phase 5: pooled from LDS (rows >= len already zero) ----
    {
        float acc = 0.f;
        for (int l = wave; l < NL; l += 4)
            acc += sc_w[l] * (float)histA[l * HST + lane];
        pp[wave * 64 + lane] = acc;
    }
    __syncthreads();
    if (tid < 64) pooled[tid] = pp[tid] + pp[64 + tid] + pp[128 + tid] + pp[192 + tid];
    __syncthreads();

    // ---- phase 6: comb = [tgt, pooled, pooled - tgt] ----
    if (tid < 192) {
        float v;
        if (tid < 64)       v = tgt[tid];
        else if (tid < 128) v = pooled[tid - 64];
        else                v = pooled[tid - 128] - tgt[tid - 128];
        comb_ws[(long)b * 192 + tid] = v;
    }
}

__global__ __launch_bounds__(256)
void din_kernel2(const float* __restrict__ comb,
                 const float* __restrict__ fW1, const float* __restrict__ fb1,
                 const float* __restrict__ fW2, const float* __restrict__ fb2,
                 const float* __restrict__ fW3, const float* __restrict__ fb3,
                 float* __restrict__ out)
{
    __shared__ float combs[4 * 192];
    __shared__ float z1s[4 * 128];
    const int tid = threadIdx.x;
    const int rb  = blockIdx.x * 4;

    for (int i = tid; i < 4 * 192; i += 256) combs[i] = comb[(long)rb * 192 + i];
    __syncthreads();

    {
        const int j  = tid & 127;
        const int r0 = (tid >> 7) * 2, r1 = r0 + 1;
        float a0 = fb1[j], a1 = a0;
        #pragma unroll 4
        for (int i = 0; i < 192; ++i) {
            float w = fW1[i * 128 + j];
            a0 += combs[r0 * 192 + i] * w;
            a1 += combs[r1 * 192 + i] * w;
        }
        z1s[r0 * 128 + j] = fmaxf(a0, 0.f);
        z1s[r1 * 128 + j] = fmaxf(a1, 0.f);
    }
    __syncthreads();

    {
        const int j2 = tid & 63;
        const int r2 = tid >> 6;
        float acc = fb2[j2];
        #pragma unroll 4
        for (int i = 0; i < 128; ++i)
            acc += z1s[r2 * 128 + i] * fW2[i * 64 + j2];
        float s = fmaxf(acc, 0.f) * fW3[j2];
        #pragma unroll
        for (int off = 1; off < 64; off <<= 1) s += __shfl_xor(s, off, 64);
        if (j2 == 0) out[rb + r2] = 1.f / (1.f + __expf(-(s + fb3[0])));
    }
}

extern "C" void kernel_launch(void* const* d_in, const int* in_sizes, int n_in,
                              void* d_out, int out_size, void* d_ws, size_t ws_size,
                              hipStream_t stream) {
    const int*   item_ids = (const int*)d_in[0];
    const int*   history  = (const int*)d_in[1];
    const int*   hist_len = (const int*)d_in[2];
    const float* emb      = (const float*)d_in[3];
    const float* aW1      = (const float*)d_in[4];
    const float* ab1      = (const float*)d_in[5];
    const float* aW2      = (const float*)d_in[6];
    // d_in[7] = ab2: softmax shift-invariance -> exactly cancels, unused
    const float* fW1      = (const float*)d_in[8];
    const float* fb1      = (const float*)d_in[9];
    const float* fW2      = (const float*)d_in[10];
    const float* fb2      = (const float*)d_in[11];
    const float* fW3      = (const float*)d_in[12];
    const float* fb3      = (const float*)d_in[13];

    const size_t embh_bytes = (size_t)NV * ND * sizeof(bf16_t);   // 12.8 MB
    const size_t comb_bytes = (size_t)NB * 192 * sizeof(float);   // 3.1 MB
    const bool   use_bt     = ws_size >= embh_bytes + comb_bytes;

    if (use_bt) {
        bf16_t* embh = (bf16_t*)d_ws;
        float*  comb = (float*)((char*)d_ws + embh_bytes);
        din_cvt<<<(NV * ND) / (256 * 8), 256, 0, stream>>>(emb, embh);
        din_kernel1<true><<<NB, 256, 0, stream>>>(item_ids, history, hist_len, emb,
                                                  embh, aW1, ab1, aW2, comb);
        din_kernel2<<<NB / 4, 256, 0, stream>>>(comb, fW1, fb1, fW2, fb2, fW3, fb3,
                                                (float*)d_out);
    } else {
        float* comb = (float*)d_ws;
        din_kernel1<false><<<NB, 256, 0, stream>>>(item_ids, history, hist_len, emb,
                                                   (const bf16_t*)nullptr, aW1, ab1, aW2, comb);
        din_kernel2<<<NB / 4, 256, 0, stream>>>(comb, fW1, fb1, fW2, fb2, fW3, fb3,
                                                (float*)d_out);
    }
}